// Round 2
// baseline (960.010 us; speedup 1.0000x reference)
//
#include <hip/hip_runtime.h>
#include <hip/hip_bf16.h>
#include <math.h>

#define EMBED_DIM 512
#define NUM_CLASSES 100000
#define NUM_SUB 3
#define BATCH 256
#define M_TOTAL (NUM_CLASSES*NUM_SUB)   // 300000
#define BM 48                            // weight rows per block = 16 whole classes
#define BK 64
#define LDB 72                           // padded bf16 stride for B tile
#define NBLOCKS (M_TOTAL/BM)             // 6250

typedef float  floatx4 __attribute__((ext_vector_type(4)));
typedef __bf16 bf16x8  __attribute__((ext_vector_type(8)));

// round-to-nearest-even fp32 -> bf16 (bit trick)
__device__ __forceinline__ unsigned int f2bf(float f){
  unsigned int u = __float_as_uint(f);
  u += 0x7FFFu + ((u >> 16) & 1u);
  return u >> 16;
}

// ---------------- kernel 1: normalize embeddings, pack bf16, K-tile-major ----
// ehat layout: [kt=K/64][batch=256][64] bf16 (262 KB -> L2-resident); the GEMM
// kernel gathers A fragments straight from it.
__global__ __launch_bounds__(64) void normalize_pack(
    const float* __restrict__ E, unsigned short* __restrict__ ehat)
{
  const int r    = blockIdx.x;     // batch row
  const int lane = threadIdx.x;    // 64 lanes, 8 floats each
  const float4 v0 = *(const float4*)(E + r*EMBED_DIM + lane*8);
  const float4 v1 = *(const float4*)(E + r*EMBED_DIM + lane*8 + 4);
  float ssq = v0.x*v0.x + v0.y*v0.y + v0.z*v0.z + v0.w*v0.w
            + v1.x*v1.x + v1.y*v1.y + v1.z*v1.z + v1.w*v1.w;
  #pragma unroll
  for (int m = 1; m < 64; m <<= 1) ssq += __shfl_xor(ssq, m, 64);
  float nn = sqrtf(ssq);
  nn = fmaxf(nn, 1e-12f);           // matches F.normalize eps semantics
  const float rn = 1.0f / nn;
  const float vals[8] = {v0.x, v0.y, v0.z, v0.w, v1.x, v1.y, v1.z, v1.w};
  unsigned int p[4];
  #pragma unroll
  for (int i = 0; i < 4; ++i)
    p[i] = f2bf(vals[2*i]*rn) | (f2bf(vals[2*i+1]*rn) << 16);
  const int kt = lane >> 3;                       // (lane*8)/64
  const size_t off = (size_t)kt*(BATCH*BK) + (size_t)r*BK + (lane & 7)*8;
  *(uint4*)(ehat + off) = make_uint4(p[0], p[1], p[2], p[3]);
}

// ---------------- kernel 2: fused GEMM + norm + subcenter-max + margin + exp --
// One barrier per K-step. B[kt+1] is loaded into registers at the top of
// segment kt (drained by the segment-end barrier => zero wait when consumed
// next segment); bf16 tile is double-buffered and converted one segment ahead.
// A fragments come register-direct from L2-resident ehat.
__global__ __launch_bounds__(256, 3) void arcface_main(
    const float* __restrict__ W,            // [300000][512] fp32 row-major
    const unsigned short* __restrict__ ehat,// blocked bf16 (see above)
    const int* __restrict__ labels,
    float* __restrict__ gsum,               // [256] stride-16 fp32 accumulators
    float* __restrict__ llogit)             // [256] fp32, 64*phi at label class
{
  __builtin_assume(threadIdx.x < 256);
  // LDS: bf16 tile ping-pong 2 x [48][72] (13824 B);
  //      epilogue reuses the region as 4 x [16][49] fp32 (12544 B)
  __shared__ char  smem[13824];
  __shared__ float snorm[BM];

  const int tid  = threadIdx.x;
  const int wave = tid >> 6, lane = tid & 63;
  const int m0   = blockIdx.x * BM;
  const int r16  = tid >> 4, c4 = tid & 15;    // B staging: 16 threads per row
  const int col  = lane & 15, quad = lane >> 4;

  unsigned short* tile = (unsigned short*)smem;  // 2 x 48*LDB bf16

  floatx4 acc[12] = {};                 // wave: 4 row-tiles(batch) x 3 col-tiles(weight)
  float ssq_acc[3] = {0,0,0};

  // A fragment base: row = wave*64 + rt*16 + col, k = kt*64 + h*32 + quad*8
  const unsigned short* abase = ehat + (wave*64 + col)*64 + quad*8;
  // B staging: thread handles rows i*16 + r16, cols kt*64 + c4*4
  const float* wbase = W + (size_t)m0*EMBED_DIM + c4*4;

  bf16x8 a[4][2];
  float4 bv[2][3];                      // W[kt] lives in bv[kt&1] (static idx after unroll)

  // ---------------- prologue ------------------------------------------------
  #pragma unroll
  for (int i = 0; i < 3; ++i)           // W[0]
    bv[0][i] = *(const float4*)(wbase + (size_t)(i*16 + r16)*EMBED_DIM);
  #pragma unroll
  for (int i = 0; i < 3; ++i)           // W[1] (stays in flight past convert)
    bv[1][i] = *(const float4*)(wbase + (size_t)(i*16 + r16)*EMBED_DIM + BK);
  #pragma unroll
  for (int rt = 0; rt < 4; ++rt)        // A[0] (L2)
    #pragma unroll
    for (int h = 0; h < 2; ++h)
      a[rt][h] = *(const bf16x8*)(abase + rt*1024 + h*32);
  { // convert W[0] -> tile[0]
    unsigned short* tw = tile;          // parity 0
    #pragma unroll
    for (int i = 0; i < 3; ++i){
      const float4 v = bv[0][i];
      ssq_acc[i] += v.x*v.x + v.y*v.y + v.z*v.z + v.w*v.w;
      const int row = i*16 + r16;
      *(uint2*)(tw + row*LDB + c4*4) =
          make_uint2(f2bf(v.x) | (f2bf(v.y) << 16), f2bf(v.z) | (f2bf(v.w) << 16));
    }
  }
  __syncthreads();   // tile[0] visible; W[1]/A[0] drained

  // ---------------- main loop: one barrier per K-step -----------------------
  #pragma unroll
  for (int s = 0; s < 8; ++s){
    // 1) issue B[s+2] into bv[s&1] (drains at this segment's barrier)
    if (s < 6){
      #pragma unroll
      for (int i = 0; i < 3; ++i)
        bv[s & 1][i] = *(const float4*)(wbase + (size_t)(i*16 + r16)*EMBED_DIM + (s+2)*BK);
    }
    // 2) convert W[s+1] (bv[(s+1)&1], already drained) -> tile[(s+1)&1]
    if (s < 7){
      unsigned short* tw = tile + ((s+1) & 1)*(48*LDB);
      #pragma unroll
      for (int i = 0; i < 3; ++i){
        const float4 v = bv[(s+1) & 1][i];
        ssq_acc[i] += v.x*v.x + v.y*v.y + v.z*v.z + v.w*v.w;
        const int row = i*16 + r16;
        *(uint2*)(tw + row*LDB + c4*4) =
            make_uint2(f2bf(v.x) | (f2bf(v.y) << 16), f2bf(v.z) | (f2bf(v.w) << 16));
      }
    }
    // 3) MFMA on tile[s&1] (converted last segment, barrier'd) x a (drained)
    {
      const unsigned short* tr = tile + (s & 1)*(48*LDB);
      #pragma unroll
      for (int h = 0; h < 2; ++h){
        bf16x8 b[3];
        #pragma unroll
        for (int ct = 0; ct < 3; ++ct)
          b[ct] = *(const bf16x8*)(tr + (ct*16 + col)*LDB + h*32 + quad*8);
        #pragma unroll
        for (int rt = 0; rt < 4; ++rt)
          #pragma unroll
          for (int ct = 0; ct < 3; ++ct)
            acc[rt*3 + ct] = __builtin_amdgcn_mfma_f32_16x16x32_bf16(
                a[rt][h], b[ct], acc[rt*3 + ct], 0, 0, 0);
      }
    }
    // 4) reload A[s+1] (L2; drains at this barrier, zero wait next segment)
    if (s < 7){
      #pragma unroll
      for (int rt = 0; rt < 4; ++rt)
        #pragma unroll
        for (int h = 0; h < 2; ++h)
          a[rt][h] = *(const bf16x8*)(abase + (s+1)*16384 + rt*1024 + h*32);
    }
    __syncthreads();
  }

  // ---- finalize per-row weight norms (16 staging lanes share a row) --------
  #pragma unroll
  for (int it = 0; it < 3; ++it){
    float s = ssq_acc[it];
    s += __shfl_xor(s, 1, 64); s += __shfl_xor(s, 2, 64);
    s += __shfl_xor(s, 4, 64); s += __shfl_xor(s, 8, 64);
    if (c4 == 0) snorm[it*16 + r16] = s;
  }
  __syncthreads();

  // ---- epilogue: cosine -> LDS -> subcenter max -> margin -> exp-sum -------
  float rnorm3[3];
  #pragma unroll
  for (int i = 0; i < 3; ++i){
    float nw = sqrtf(snorm[i*16 + col]);
    rnorm3[i] = 1.0f / fmaxf(nw, 1e-12f);
  }
  float* ebuf = (float*)smem + wave*(16*49);   // per-wave private 3.1 KB slice
  const int cls0 = m0 / 3;
  const float cos_m = 0.87758256189037276f;
  const float sin_m = 0.47942553860420301f;
  const float thr   = -0.87758256189037276f;   // cos(pi - m)
  const float mmv   = 0.23971276930210156f;    // sin(pi - m)*m

  #pragma unroll
  for (int rt = 0; rt < 4; ++rt){
    // write this chunk's 16 x 48 cosines (stride 49)
    #pragma unroll
    for (int ct = 0; ct < 3; ++ct)
      #pragma unroll
      for (int r = 0; r < 4; ++r)
        ebuf[(quad*4 + r)*49 + ct*16 + col] = acc[rt*3 + ct][r] * rnorm3[ct];
    __syncthreads();
    // read phase: lanes 0..15 each own one batch row of this chunk
    if (quad == 0){
      const int brow = wave*64 + rt*16 + col;
      const int lbl  = labels[brow];
      float contrib = 0.0f;
      for (int c = 0; c < 16; ++c){
        const float a0 = ebuf[col*49 + 3*c + 0];
        const float a1 = ebuf[col*49 + 3*c + 1];
        const float a2 = ebuf[col*49 + 3*c + 2];
        float cm = fmaxf(a0, fmaxf(a1, a2));
        float val = cm;
        if (cls0 + c == lbl){
          const float sine = sqrtf(fmaxf(0.0f, 1.0f - cm*cm));
          const float phi  = cm*cos_m - sine*sin_m;
          val = (cm > thr) ? phi : (cm - mmv);
          llogit[brow] = 64.0f * val;
        }
        contrib += __expf(64.0f*val - 64.0f);   // logits <= 64 always -> safe shift
      }
      atomicAdd(&gsum[brow*16], contrib);
    }
    __syncthreads();
  }
}

// ---------------- kernel 3: loss = mean(log(sum) + 64 - label_logit) --------
__global__ __launch_bounds__(256) void finalize_loss(
    const float* __restrict__ gsum, const float* __restrict__ llogit,
    float* __restrict__ out)
{
  const int tid = threadIdx.x;
  float v = logf(gsum[tid*16]) + 64.0f - llogit[tid];
  #pragma unroll
  for (int m = 1; m < 64; m <<= 1) v += __shfl_xor(v, m, 64);
  __shared__ float red[4];
  if ((tid & 63) == 0) red[tid >> 6] = v;
  __syncthreads();
  if (tid == 0) out[0] = (red[0] + red[1] + red[2] + red[3]) * (1.0f/BATCH);
}

extern "C" void kernel_launch(void* const* d_in, const int* in_sizes, int n_in,
                              void* d_out, int out_size, void* d_ws, size_t ws_size,
                              hipStream_t stream)
{
  const float* emb    = (const float*)d_in[0];
  const int*   labels = (const int*)d_in[1];
  const float* W      = (const float*)d_in[2];

  // workspace layout: ehat bf16 blocked (262144 B) | gsum (16384 B) | llogit (1024 B)
  unsigned short* ehat   = (unsigned short*)d_ws;
  float*          gsum   = (float*)((char*)d_ws + 262144);
  float*          llogit = (float*)((char*)d_ws + 262144 + 16384);

  hipMemsetAsync(gsum, 0, 16384, stream);
  normalize_pack<<<BATCH, 64, 0, stream>>>(emb, ehat);
  arcface_main<<<NBLOCKS, 256, 0, stream>>>(W, ehat, labels, gsum, llogit);
  finalize_loss<<<1, 256, 0, stream>>>(gsum, llogit, (float*)d_out);
}